// Round 15
// baseline (264.428 us; speedup 1.0000x reference)
//
#include <hip/hip_runtime.h>

// NavAssignNet on MI355X — round 15: R14 + bigpass epilogue rowbias staged in
// LDS (16 coalesced float4/thread replace 64 scalar VMEM loads; stride-260 pad
// kills the 4-row bank alias). NO tile split this time — R11's A/B isolated
// R9's regression to doubled A-traffic, not the LDS staging.

typedef short bf16x8 __attribute__((ext_vector_type(8)));
typedef float f32x4 __attribute__((ext_vector_type(4)));

#define DEV static __device__ __forceinline__

DEV unsigned short f2bf(float x) {
    unsigned u = __float_as_uint(x);
    return (unsigned short)((u + 0x7fffu + ((u >> 16) & 1u)) >> 16);
}
DEV void split2(float v, unsigned short& hi, unsigned short& lo) {
    unsigned short h = f2bf(v);
    float fh = __uint_as_float(((unsigned)h) << 16);
    hi = h;
    lo = f2bf(v - fh);
}

// ---- 1. prep+weights merged ----
__global__ __launch_bounds__(256) void k_prep_w(const float* __restrict__ edge,
                                                unsigned short* __restrict__ edge_bf,
                                                float* __restrict__ traw,
                                                const float* __restrict__ Wp,
                                                const float* __restrict__ bp,
                                                const float* __restrict__ W_r2t,
                                                const float* __restrict__ b_r2t,
                                                const float* __restrict__ W_t2r,
                                                const float* __restrict__ b_t2r,
                                                const float* __restrict__ W_pt,
                                                const float* __restrict__ W_pr,
                                                const float* __restrict__ Ws1,
                                                unsigned short* __restrict__ WcT,
                                                float* __restrict__ bc,
                                                unsigned short* __restrict__ WTbig,
                                                unsigned short* __restrict__ WT2) {
    if (blockIdx.x < 512) {
        int wg = blockIdx.x;             // b*64 + j
        int b = wg >> 6, j = wg & 63;
        int t = threadIdx.x;
        int d = t & 127, ih = t >> 7;
        float s = 0.f;
        long base = ((long)(b * 64 + ih * 32) * 64 + j) * 128 + d;
#pragma unroll 8
        for (int ii = 0; ii < 32; ++ii) {
            long idx = base + (long)ii * 8192;
            float v = edge[idx];
            s += v;
            edge_bf[idx] = f2bf(v);
        }
        __shared__ float part[128];
        if (ih == 1) part[d] = s;
        __syncthreads();
        if (ih == 0) traw[(b * 64 + j) * 128 + d] = (s + part[d]) * (1.f / 64.f);
        return;
    }
    int blk0 = blockIdx.x - 512;
    int h = threadIdx.x;
    if (blk0 < 774) {
        int blk = blk0;
        if (blk < 768) {
            int p = blk >> 7, d = blk & 127, l = p >> 1;
            const float* Wb = ((p & 1) ? W_t2r : W_r2t) + l * 512 * 256 + 256 * 256;
            float acc = 0.f;
            for (int k = 0; k < 256; ++k) acc += Wp[d * 256 + k] * Wb[k * 256 + h];
            WcT[p * 32768 + h * 128 + d] = f2bf(acc);
        } else {
            int p = blk - 768, l = p >> 1;
            const float* Wb = ((p & 1) ? W_t2r : W_r2t) + l * 512 * 256 + 256 * 256;
            const float* bm = ((p & 1) ? b_t2r : b_r2t) + l * 256;
            float acc = bm[h];
            for (int k = 0; k < 256; ++k) acc += bp[k] * Wb[k * 256 + h];
            bc[p * 256 + h] = acc;
        }
        return;
    }
    int blk = blk0 - 774, t = threadIdx.x;
    if (blk < 1536) {
        // WTbig: hi plane only
        int mat = blk >> 8, hh = blk & 255, l = mat >> 1;
        const float* W = ((mat & 1) ? W_pr : W_pt) + l * 512 * 256;
        unsigned short* dh = WTbig + mat * 262144 + hh * 512;
        for (int k = t; k < 512; k += 256)
            dh[k] = f2bf(W[k * 256 + hh]);
    } else {
        // WT2: hi plane only
        int m2 = blk - 1536, mat = m2 >> 8, hh = m2 & 255;
        const float* W;
        if (mat == 6) W = Ws1 + 256 * 256;
        else if (mat == 5) W = Ws1;
        else if (mat & 1) W = W_r2t + ((mat >> 1) + 1) * 512 * 256;
        else W = W_t2r + (mat >> 1) * 512 * 256;
        WT2[mat * 65536 + hh * 256 + t] = f2bf(W[t * 256 + hh]);
    }
}

// ---- 2. proj: robot_h/target_h = X @ Wp + bp ; robot WGs also emit rWa0 ----
__global__ __launch_bounds__(256) void k_proj(const float* __restrict__ robot_raw,
                                              const float* __restrict__ traw,
                                              const float* __restrict__ Wp,
                                              const float* __restrict__ bp,
                                              const float* __restrict__ Wa0,
                                              float* __restrict__ robot_h,
                                              float* __restrict__ target_h,
                                              float* __restrict__ rWa) {
    int h = threadIdx.x;
    int r0 = blockIdx.x * 2;
    int robot = (r0 < 512);
    const float* in;
    float* out;
    if (robot) { in = robot_raw + r0 * 128; out = robot_h + r0 * 256; }
    else       { in = traw + (r0 - 512) * 128; out = target_h + (r0 - 512) * 256; }
    float a0 = 0, a1 = 0;
    for (int k = 0; k < 128; ++k) {
        float w = Wp[k * 256 + h];
        a0 += in[k] * w; a1 += in[128 + k] * w;
    }
    float b = bp[h];
    a0 += b; a1 += b;
    out[h] = a0; out[256 + h] = a1;

    __shared__ float yl[2][257];
    if (robot) { yl[0][h] = a0; yl[1][h] = a1; }
    __syncthreads();
    if (robot) {
        float c0 = 0, c1 = 0;
        for (int k = 0; k < 256; ++k) {
            float w = Wa0[k * 256 + h];
            c0 += yl[0][k] * w; c1 += yl[1][k] * w;
        }
        rWa[r0 * 256 + h] = c0; rWa[(r0 + 1) * 256 + h] = c1;
    }
}

// ---- 3. update via MFMA split-bf16, 1024 threads / 16 waves (16 cols each) ----
// Both GEMMs 2-term. Optional fused scores phase (last robot update).
__global__ __launch_bounds__(1024) void k_update_mfma(
        float* __restrict__ state, const float* __restrict__ agg,
        const unsigned short* __restrict__ WTm,   // [hi 256x512]
        const float* __restrict__ bvec, const float* __restrict__ g, const float* __restrict__ be,
        const unsigned short* __restrict__ WT2a,  // [hi 256x256]
        float* __restrict__ out2a,
        const unsigned short* __restrict__ WT2b, const float* __restrict__ b2b,
        float* __restrict__ out2b,
        const float* __restrict__ tSTg, const float* __restrict__ Ws2v,
        const float* __restrict__ bs2v, float* __restrict__ scoresOut) {
    int r0 = blockIdx.x * 16;
    int t = threadIdx.x;
    int w = t >> 6, lane = t & 63;
    int c16 = lane & 15, kg = lane >> 4;
    int col = (w << 4) | c16;

    __shared__ unsigned short Ahi[16 * 512];
    __shared__ unsigned short Alo[16 * 512];
    __shared__ unsigned short Yhi[16 * 256];
    __shared__ unsigned short Ylo[16 * 256];
    __shared__ float red[16][16][2];

    // preload first 4 main-GEMM B fragments (in flight across the staging phase)
    const unsigned short* Bh0 = WTm + col * 512 + kg * 8;
    bf16x8 bp0 = *(const bf16x8*)(Bh0);
    bf16x8 bp1 = *(const bf16x8*)(Bh0 + 32);
    bf16x8 bp2 = *(const bf16x8*)(Bh0 + 64);
    bf16x8 bp3 = *(const bf16x8*)(Bh0 + 96);

    // stage A = [state | agg] rows r0..r0+15 as swizzled hi/lo bf16 (8 elems/thread)
    {
        int row = t & 15, kq = t >> 4;   // kq 0..63 -> 8 K-elems each
        const float* src = (kq < 32) ? (state + (r0 + row) * 256 + kq * 8)
                                     : (agg + (r0 + row) * 256 + (kq - 32) * 8);
        float4 a = *(const float4*)(src);
        float4 b2 = *(const float4*)(src + 4);
        unsigned short h[8], lo[8];
        split2(a.x, h[0], lo[0]); split2(a.y, h[1], lo[1]);
        split2(a.z, h[2], lo[2]); split2(a.w, h[3], lo[3]);
        split2(b2.x, h[4], lo[4]); split2(b2.y, h[5], lo[5]);
        split2(b2.z, h[6], lo[6]); split2(b2.w, h[7], lo[7]);
        int byte = row * 1024 + kq * 16;
        byte ^= (row & 7) << 4;
        ushort4* ph = (ushort4*)((char*)Ahi + byte);
        ph[0] = make_ushort4(h[0], h[1], h[2], h[3]);
        ph[1] = make_ushort4(h[4], h[5], h[6], h[7]);
        ushort4* pl = (ushort4*)((char*)Alo + byte);
        pl[0] = make_ushort4(lo[0], lo[1], lo[2], lo[3]);
        pl[1] = make_ushort4(lo[4], lo[5], lo[6], lo[7]);
    }
    __syncthreads();

    // main GEMM: K=512, 2-term split, 1 col-tile per wave
    f32x4 acc = f32x4{0.f, 0.f, 0.f, 0.f};
#pragma unroll
    for (int ks = 0; ks < 16; ++ks) {
        int ab = c16 * 1024 + ks * 64 + kg * 16;
        ab ^= (c16 & 7) << 4;
        bf16x8 ah = *(const bf16x8*)((const char*)Ahi + ab);
        bf16x8 al = *(const bf16x8*)((const char*)Alo + ab);
        bf16x8 bh = (ks == 0) ? bp0 : (ks == 1) ? bp1 : (ks == 2) ? bp2 : (ks == 3) ? bp3
                                  : *(const bf16x8*)(Bh0 + ks * 32);
        acc = __builtin_amdgcn_mfma_f32_16x16x32_bf16(ah, bh, acc, 0, 0, 0);
        acc = __builtin_amdgcn_mfma_f32_16x16x32_bf16(al, bh, acc, 0, 0, 0);
    }

    // residual + bias
    float x[4];
    {
        float bv = bvec[col];
#pragma unroll
        for (int r = 0; r < 4; ++r) {
            int row = kg * 4 + r;
            x[r] = acc[r] + state[(r0 + row) * 256 + col] + bv;
        }
    }

    // LN stats: reduce over 16 cols in-wave, then 16 waves via LDS
    float s[4], q[4];
#pragma unroll
    for (int r = 0; r < 4; ++r) {
        s[r] = x[r];
        q[r] = x[r] * x[r];
#pragma unroll
        for (int m = 1; m < 16; m <<= 1) {
            s[r] += __shfl_xor(s[r], m);
            q[r] += __shfl_xor(q[r], m);
        }
    }
    if (c16 == 0) {
#pragma unroll
        for (int r = 0; r < 4; ++r) {
            red[w][kg * 4 + r][0] = s[r];
            red[w][kg * 4 + r][1] = q[r];
        }
    }
    __syncthreads();
    float mr[4], rsr[4];
#pragma unroll
    for (int r = 0; r < 4; ++r) {
        int row = kg * 4 + r;
        float S = 0.f, Q = 0.f;
#pragma unroll
        for (int w2 = 0; w2 < 16; ++w2) { S += red[w2][row][0]; Q += red[w2][row][1]; }
        float m = S * (1.f / 256.f);
        float v = Q * (1.f / 256.f) - m * m;
        mr[r] = m;
        rsr[r] = rsqrtf(v + 1e-5f);
    }

    // y = LN(x): store to state + stage bf16 hi/lo into LDS (swizzled)
    {
        float gg = g[col], bb = be[col];
#pragma unroll
        for (int r = 0; r < 4; ++r) {
            int row = kg * 4 + r;
            float y = (x[r] - mr[r]) * rsr[r] * gg + bb;
            state[(r0 + row) * 256 + col] = y;
            unsigned short yh, yl2;
            split2(y, yh, yl2);
            int byte = (row * 512 + col * 2) ^ ((row & 7) << 4);
            *(unsigned short*)((char*)Yhi + byte) = yh;
            *(unsigned short*)((char*)Ylo + byte) = yl2;
        }
    }
    __syncthreads();

    // fused GEMM(s), 2-term: y @ W2a, optional y @ W2b + b2b (-> out2b T)
    f32x4 acc2 = f32x4{0.f, 0.f, 0.f, 0.f};
    f32x4 acc3 = f32x4{0.f, 0.f, 0.f, 0.f};
    const unsigned short* B2h0 = WT2a + col * 256 + kg * 8;
    const unsigned short* B3h0 = WT2b ? (WT2b + col * 256 + kg * 8) : B2h0;
    int haveB = (WT2b != nullptr);
#pragma unroll 4
    for (int ks = 0; ks < 8; ++ks) {
        int ab = c16 * 512 + ks * 64 + kg * 16;
        ab ^= (c16 & 7) << 4;
        bf16x8 ah = *(const bf16x8*)((const char*)Yhi + ab);
        bf16x8 al = *(const bf16x8*)((const char*)Ylo + ab);
        bf16x8 bh = *(const bf16x8*)(B2h0 + ks * 32);
        acc2 = __builtin_amdgcn_mfma_f32_16x16x32_bf16(ah, bh, acc2, 0, 0, 0);
        acc2 = __builtin_amdgcn_mfma_f32_16x16x32_bf16(al, bh, acc2, 0, 0, 0);
        if (haveB) {
            bf16x8 bh3 = *(const bf16x8*)(B3h0 + ks * 32);
            acc3 = __builtin_amdgcn_mfma_f32_16x16x32_bf16(ah, bh3, acc3, 0, 0, 0);
            acc3 = __builtin_amdgcn_mfma_f32_16x16x32_bf16(al, bh3, acc3, 0, 0, 0);
        }
    }
    if (!scoresOut) {
#pragma unroll
        for (int r = 0; r < 4; ++r) {
            int row = kg * 4 + r;
            out2a[(r0 + row) * 256 + col] = acc2[r];
        }
    }
    if (haveB) {
        float bb2 = b2b[col];
#pragma unroll
        for (int r = 0; r < 4; ++r) {
            int grow = r0 + kg * 4 + r;
            int b0 = grow >> 6, j = grow & 63;
            out2b[(b0 * 256 + col) * 64 + j] = acc3[r] + bb2;
        }
    }

    // fused scores phase (last robot update): rS rows live in LDS (alias Ahi)
    if (scoresOut) {
        float* rSl = (float*)Ahi;        // 16x256 f32 = 16KB, Ahi is dead
#pragma unroll
        for (int r = 0; r < 4; ++r)
            rSl[(kg * 4 + r) * 256 + col] = acc2[r];
        __syncthreads();
        int il = t >> 6, j = t & 63;     // 16 rows x 64 cols = 1024 threads
        int grow = r0 + il, b0 = grow >> 6;
        const float* ts = tSTg + b0 * 16384 + j;
        const float* rsrow = rSl + il * 256;
        float accs = bs2v[0];
        for (int h = 0; h < 256; ++h)
            accs += fmaxf(rsrow[h] + ts[h * 64], 0.f) * Ws2v[h];
        scoresOut[grow * 64 + j] = accs;
    }
}

// ---- 4. bigpass: hoisted loads; LDS-staged rowbias epilogue; mid-kernel prefetch ----
__global__ __launch_bounds__(256) void k_bigpass(const unsigned short* __restrict__ edge_bf,
                                                 const unsigned short* __restrict__ WcT,
                                                 const float* __restrict__ bc,
                                                 const float* __restrict__ rowbias,
                                                 float* __restrict__ agg,
                                                 int mode,
                                                 const unsigned short* __restrict__ prefA,
                                                 const unsigned short* __restrict__ prefB,
                                                 int nb) {            // nb = uint4 count of B slice
    int wg = blockIdx.x;                 // 512 = b*64 + jj
    int b = wg >> 6, jj = wg & 63;
    int w = threadIdx.x >> 6, lane = threadIdx.x & 63;
    int row16 = lane & 15, kgrp = lane >> 4;

    __shared__ float rbl[64 * 260];      // 64 rows x 256 cols, stride 260 (bank-alias pad)

    // stage full rowbias panel: 16 coalesced float4/thread (replaces 64 scalar loads)
    {
        const float* rbsrc = rowbias + (b * 64) * 256;
#pragma unroll
        for (int k = 0; k < 16; ++k) {
            int f = k * 256 + threadIdx.x;   // 0..4095 float4 slots
            int row = f >> 6, c4 = f & 63;
            float4 vv = *(const float4*)(rbsrc + row * 256 + c4 * 4);
            *(float4*)(&rbl[row * 260 + c4 * 4]) = vv;
        }
    }

    int rstride = (mode == 0) ? 8192 : 128;
    const unsigned short* Ap = edge_bf + b * 524288 + ((mode == 0) ? jj * 128 : jj * 8192)
                             + row16 * rstride + 8 * kgrp;
    const unsigned short* Bp = WcT + (64 * w + row16) * 128 + 8 * kgrp;

    // hoist ALL fragment loads: one latency window
    bf16x8 av[4][4], bv[4][4];
#pragma unroll
    for (int kk = 0; kk < 4; ++kk) {
#pragma unroll
        for (int mi = 0; mi < 4; ++mi)
            av[mi][kk] = *(const bf16x8*)(Ap + mi * 16 * rstride + kk * 32);
#pragma unroll
        for (int ni = 0; ni < 4; ++ni)
            bv[ni][kk] = *(const bf16x8*)(Bp + ni * 2048 + kk * 32);
    }
    __builtin_amdgcn_sched_barrier(0);

    f32x4 acc[4][4];
#pragma unroll
    for (int mi = 0; mi < 4; ++mi)
#pragma unroll
        for (int ni = 0; ni < 4; ++ni) acc[mi][ni] = f32x4{0.f, 0.f, 0.f, 0.f};
#pragma unroll
    for (int kk = 0; kk < 4; ++kk)
#pragma unroll
        for (int mi = 0; mi < 4; ++mi)
#pragma unroll
            for (int ni = 0; ni < 4; ++ni)
                acc[mi][ni] = __builtin_amdgcn_mfma_f32_16x16x32_bf16(av[mi][kk], bv[ni][kk], acc[mi][ni], 0, 0, 0);

    // issue prefetch loads now (next update's weight panels, 1/64 slice)
    int s = (blockIdx.x >> 3) & 63;
    const uint4* pa = (const uint4*)prefA + (long)s * 256;
    const uint4* pb = (const uint4*)prefB + (long)s * nb;
    uint4 pf0 = pa[threadIdx.x];
    uint4 pf2;
    int i0 = threadIdx.x & (nb - 1);
    pf2 = pb[i0];
    uint4 pf3;
    int big = (nb > 128);
    if (big) pf3 = pb[128 + (threadIdx.x & 255)];
    __builtin_amdgcn_sched_barrier(0);

    __syncthreads();   // rowbias panel ready

    float colsum[4] = {0.f, 0.f, 0.f, 0.f};
#pragma unroll
    for (int ni = 0; ni < 4; ++ni) {
        int col = 64 * w + 16 * ni + row16;
        float bch = bc[col];
#pragma unroll
        for (int mi = 0; mi < 4; ++mi) {
            int rbase = 16 * mi + 4 * kgrp;
#pragma unroll
            for (int r = 0; r < 4; ++r) {
                float v = acc[mi][ni][r] + rbl[(rbase + r) * 260 + col] + bch;
                colsum[ni] += fmaxf(v, 0.f);
            }
        }
    }
#pragma unroll
    for (int ni = 0; ni < 4; ++ni) {
        colsum[ni] += __shfl_xor(colsum[ni], 16);
        colsum[ni] += __shfl_xor(colsum[ni], 32);
    }
    if (kgrp == 0) {
        float* o = agg + (b * 64 + jj) * 256 + 64 * w + row16;
#pragma unroll
        for (int ni = 0; ni < 4; ++ni) o[16 * ni] = colsum[ni] * (1.f / 64.f);
    }

    unsigned accp = pf0.x ^ pf0.w ^ pf2.z;
    if (big) accp ^= pf3.x;
    asm volatile("" :: "v"(accp));
}

// ---- 5. sinkhorn: 8 WGs x 1024, v[4]/thread ----
__global__ __launch_bounds__(1024) void k_sinkhorn(const float* __restrict__ scores,
                                                   float* __restrict__ probs) {
    int b = blockIdx.x;
    int t = threadIdx.x;
    int j = t & 63, rg = t >> 6;         // 16 row-groups x 4 rows
    float v[4];
    const float* src = scores + b * 4096 + rg * 256 + j;
#pragma unroll
    for (int k = 0; k < 4; ++k) v[k] = src[k * 64];

    __shared__ float lm_s[2][16][64];
    __shared__ float ps_s[2][16][64];

    for (int it = 0; it < 10; ++it) {
#pragma unroll
        for (int k = 0; k < 4; ++k) {
            float m = v[k];
#pragma unroll
            for (int s = 1; s < 64; s <<= 1) m = fmaxf(m, __shfl_xor(m, s));
            float e = __expf(v[k] - m), ss = e;
#pragma unroll
            for (int s = 1; s < 64; s <<= 1) ss += __shfl_xor(ss, s);
            v[k] -= m + __logf(ss);
        }
        int p = it & 1;
        float lm = fmaxf(fmaxf(v[0], v[1]), fmaxf(v[2], v[3]));
        float ps = __expf(v[0] - lm) + __expf(v[1] - lm) + __expf(v[2] - lm) + __expf(v[3] - lm);
        lm_s[p][rg][j] = lm; ps_s[p][rg][j] = ps;
        __syncthreads();
        float M = lm_s[p][0][j];
#pragma unroll
        for (int g2 = 1; g2 < 16; ++g2) M = fmaxf(M, lm_s[p][g2][j]);
        float S = 0.f;
#pragma unroll
        for (int g2 = 0; g2 < 16; ++g2) S += ps_s[p][g2][j] * __expf(lm_s[p][g2][j] - M);
        float lse = M + __logf(S);
#pragma unroll
        for (int k = 0; k < 4; ++k) v[k] -= lse;
    }
    float* dst = probs + b * 4096 + rg * 256 + j;
#pragma unroll
    for (int k = 0; k < 4; ++k) dst[k * 64] = __expf(v[k]);
}

extern "C" void kernel_launch(void* const* d_in, const int* in_sizes, int n_in,
                              void* d_out, int out_size, void* d_ws, size_t ws_size,
                              hipStream_t stream) {
    const float* robot_raw = (const float*)d_in[0];
    const float* edge_raw  = (const float*)d_in[1];
    const float* Wp    = (const float*)d_in[2];
    const float* bp    = (const float*)d_in[3];
    const float* W_r2t = (const float*)d_in[4];
    const float* b_r2t = (const float*)d_in[5];
    const float* W_pt  = (const float*)d_in[6];
    const float* b_pt  = (const float*)d_in[7];
    const float* g_t   = (const float*)d_in[8];
    const float* be_t  = (const float*)d_in[9];
    const float* W_t2r = (const float*)d_in[10];
    const float* b_t2r = (const float*)d_in[11];
    const float* W_pr  = (const float*)d_in[12];
    const float* b_pr  = (const float*)d_in[13];
    const float* g_r   = (const float*)d_in[14];
    const float* be_r  = (const float*)d_in[15];
    const float* Ws1   = (const float*)d_in[16];
    const float* bs1   = (const float*)d_in[17];
    const float* Ws2   = (const float*)d_in[18];
    const float* bs2   = (const float*)d_in[19];

    char* ws = (char*)d_ws;
    unsigned short* edge_bf = (unsigned short*)(ws);            // 8,388,608
    float* traw     = (float*)(ws + 8388608);                   //   262,144
    float* robot_h  = (float*)(ws + 8650752);                   //   524,288
    float* target_h = (float*)(ws + 9175040);                   //   524,288
    unsigned short* WcT = (unsigned short*)(ws + 9699328);      //   393,216
    float* bc       = (float*)(ws + 10092544);                  //     6,144
    float* rWa      = (float*)(ws + 10098688);                  //   524,288
    float* tWa      = (float*)(ws + 10622976);                  //   524,288
    float* agg      = (float*)(ws + 11147264);                  //   524,288
    float* rS       = (float*)(ws + 11671552);                  //   524,288 (dead store target)
    float* tST      = (float*)(ws + 12195840);                  //   524,288
    unsigned short* WTbig = (unsigned short*)(ws + 12720128);   // hi planes (mat stride 262144 elems)
    unsigned short* WT2   = (unsigned short*)(ws + 15865856);   // hi planes (mat stride 65536 elems)

    float* out    = (float*)d_out;
    float* probs  = out;            // output 0
    float* scores = out + 32768;    // output 1

    hipLaunchKernelGGL(k_prep_w, dim3(4614), dim3(256), 0, stream,
                       edge_raw, edge_bf, traw,
                       Wp, bp, W_r2t, b_r2t, W_t2r, b_t2r, W_pt, W_pr, Ws1, WcT, bc, WTbig, WT2);
    hipLaunchKernelGGL(k_proj, dim3(512), dim3(256), 0, stream,
                       robot_raw, traw, Wp, bp, W_r2t, robot_h, target_h, rWa);

    for (int l = 0; l < 3; ++l) {
        // r2t bigpass + prefetch of the target-update weights (hi planes)
        {
            const unsigned short* pA = WTbig + (2 * l) * 262144;
            const unsigned short* pB = WT2 + (2 * l) * 65536;
            int nb = (l == 2) ? 384 : 128;                     // l==2 covers mats 4..6
            hipLaunchKernelGGL(k_bigpass, dim3(512), dim3(256), 0, stream,
                               edge_bf, WcT + (2 * l) * 32768, bc + (2 * l) * 256, rWa, agg, 0,
                               pA, pB, nb);
        }
        const unsigned short* W2b = (l == 2) ? (WT2 + 6 * 65536) : nullptr;
        const float* b2b = (l == 2) ? bs1 : nullptr;
        float* o2b = (l == 2) ? tST : nullptr;
        hipLaunchKernelGGL(k_update_mfma, dim3(32), dim3(1024), 0, stream,
                           target_h, agg, WTbig + (2 * l) * 262144,
                           b_pt + l * 256, g_t + l * 256, be_t + l * 256,
                           WT2 + (2 * l) * 65536, tWa, W2b, b2b, o2b,
                           (const float*)nullptr, (const float*)nullptr,
                           (const float*)nullptr, (float*)nullptr);
        // t2r bigpass + prefetch of the robot-update weights
        {
            const unsigned short* pA = WTbig + (2 * l + 1) * 262144;
            int m2 = (l < 2) ? (2 * l + 1) : 5;
            const unsigned short* pB = WT2 + m2 * 65536;
            hipLaunchKernelGGL(k_bigpass, dim3(512), dim3(256), 0, stream,
                               edge_bf, WcT + (2 * l + 1) * 32768, bc + (2 * l + 1) * 256, tWa, agg, 1,
                               pA, pB, 128);
        }
        const unsigned short* W2a = (l < 2) ? (WT2 + (2 * l + 1) * 65536) : (WT2 + 5 * 65536);
        float* o2a = (l < 2) ? rWa : rS;
        const float* fTST = (l == 2) ? tST : nullptr;
        const float* fWs2 = (l == 2) ? Ws2 : nullptr;
        const float* fbs2 = (l == 2) ? bs2 : nullptr;
        float* fScores    = (l == 2) ? scores : nullptr;
        hipLaunchKernelGGL(k_update_mfma, dim3(32), dim3(1024), 0, stream,
                           robot_h, agg, WTbig + (2 * l + 1) * 262144,
                           b_pr + l * 256, g_r + l * 256, be_r + l * 256,
                           W2a, o2a, (const unsigned short*)nullptr, (const float*)nullptr, (float*)nullptr,
                           fTST, fWs2, fbs2, fScores);
    }

    hipLaunchKernelGGL(k_sinkhorn, dim3(8), dim3(1024), 0, stream, scores, probs);
}

// Round 16
// 252.344 us; speedup vs baseline: 1.0479x; 1.0479x over previous
//
#include <hip/hip_runtime.h>

// NavAssignNet on MI355X — round 16: exact revert to round 14 (measured best,
// 251.7us). R15's LDS-staged bigpass rowbias regressed +12.7us (staging
// delayed critical-path fragment loads + barrier; scalar epilogue loads were
// already free). Epilogue hypothesis refuted twice (R9/R15) — retired.
// Final structure: 13 dispatches; 911 -> 252us over the session.

typedef short bf16x8 __attribute__((ext_vector_type(8)));
typedef float f32x4 __attribute__((ext_vector_type(4)));

#define DEV static __device__ __forceinline__

DEV unsigned short f2bf(float x) {
    unsigned u = __float_as_uint(x);
    return (unsigned short)((u + 0x7fffu + ((u >> 16) & 1u)) >> 16);
}
DEV void split2(float v, unsigned short& hi, unsigned short& lo) {
    unsigned short h = f2bf(v);
    float fh = __uint_as_float(((unsigned)h) << 16);
    hi = h;
    lo = f2bf(v - fh);
}

// ---- 1. prep+weights merged ----
__global__ __launch_bounds__(256) void k_prep_w(const float* __restrict__ edge,
                                                unsigned short* __restrict__ edge_bf,
                                                float* __restrict__ traw,
                                                const float* __restrict__ Wp,
                                                const float* __restrict__ bp,
                                                const float* __restrict__ W_r2t,
                                                const float* __restrict__ b_r2t,
                                                const float* __restrict__ W_t2r,
                                                const float* __restrict__ b_t2r,
                                                const float* __restrict__ W_pt,
                                                const float* __restrict__ W_pr,
                                                const float* __restrict__ Ws1,
                                                unsigned short* __restrict__ WcT,
                                                float* __restrict__ bc,
                                                unsigned short* __restrict__ WTbig,
                                                unsigned short* __restrict__ WT2) {
    if (blockIdx.x < 512) {
        int wg = blockIdx.x;             // b*64 + j
        int b = wg >> 6, j = wg & 63;
        int t = threadIdx.x;
        int d = t & 127, ih = t >> 7;
        float s = 0.f;
        long base = ((long)(b * 64 + ih * 32) * 64 + j) * 128 + d;
#pragma unroll 8
        for (int ii = 0; ii < 32; ++ii) {
            long idx = base + (long)ii * 8192;
            float v = edge[idx];
            s += v;
            edge_bf[idx] = f2bf(v);
        }
        __shared__ float part[128];
        if (ih == 1) part[d] = s;
        __syncthreads();
        if (ih == 0) traw[(b * 64 + j) * 128 + d] = (s + part[d]) * (1.f / 64.f);
        return;
    }
    int blk0 = blockIdx.x - 512;
    int h = threadIdx.x;
    if (blk0 < 774) {
        int blk = blk0;
        if (blk < 768) {
            int p = blk >> 7, d = blk & 127, l = p >> 1;
            const float* Wb = ((p & 1) ? W_t2r : W_r2t) + l * 512 * 256 + 256 * 256;
            float acc = 0.f;
            for (int k = 0; k < 256; ++k) acc += Wp[d * 256 + k] * Wb[k * 256 + h];
            WcT[p * 32768 + h * 128 + d] = f2bf(acc);
        } else {
            int p = blk - 768, l = p >> 1;
            const float* Wb = ((p & 1) ? W_t2r : W_r2t) + l * 512 * 256 + 256 * 256;
            const float* bm = ((p & 1) ? b_t2r : b_r2t) + l * 256;
            float acc = bm[h];
            for (int k = 0; k < 256; ++k) acc += bp[k] * Wb[k * 256 + h];
            bc[p * 256 + h] = acc;
        }
        return;
    }
    int blk = blk0 - 774, t = threadIdx.x;
    if (blk < 1536) {
        // WTbig: hi plane only
        int mat = blk >> 8, hh = blk & 255, l = mat >> 1;
        const float* W = ((mat & 1) ? W_pr : W_pt) + l * 512 * 256;
        unsigned short* dh = WTbig + mat * 262144 + hh * 512;
        for (int k = t; k < 512; k += 256)
            dh[k] = f2bf(W[k * 256 + hh]);
    } else {
        // WT2: hi plane only
        int m2 = blk - 1536, mat = m2 >> 8, hh = m2 & 255;
        const float* W;
        if (mat == 6) W = Ws1 + 256 * 256;
        else if (mat == 5) W = Ws1;
        else if (mat & 1) W = W_r2t + ((mat >> 1) + 1) * 512 * 256;
        else W = W_t2r + (mat >> 1) * 512 * 256;
        WT2[mat * 65536 + hh * 256 + t] = f2bf(W[t * 256 + hh]);
    }
}

// ---- 2. proj: robot_h/target_h = X @ Wp + bp ; robot WGs also emit rWa0 ----
__global__ __launch_bounds__(256) void k_proj(const float* __restrict__ robot_raw,
                                              const float* __restrict__ traw,
                                              const float* __restrict__ Wp,
                                              const float* __restrict__ bp,
                                              const float* __restrict__ Wa0,
                                              float* __restrict__ robot_h,
                                              float* __restrict__ target_h,
                                              float* __restrict__ rWa) {
    int h = threadIdx.x;
    int r0 = blockIdx.x * 2;
    int robot = (r0 < 512);
    const float* in;
    float* out;
    if (robot) { in = robot_raw + r0 * 128; out = robot_h + r0 * 256; }
    else       { in = traw + (r0 - 512) * 128; out = target_h + (r0 - 512) * 256; }
    float a0 = 0, a1 = 0;
    for (int k = 0; k < 128; ++k) {
        float w = Wp[k * 256 + h];
        a0 += in[k] * w; a1 += in[128 + k] * w;
    }
    float b = bp[h];
    a0 += b; a1 += b;
    out[h] = a0; out[256 + h] = a1;

    __shared__ float yl[2][257];
    if (robot) { yl[0][h] = a0; yl[1][h] = a1; }
    __syncthreads();
    if (robot) {
        float c0 = 0, c1 = 0;
        for (int k = 0; k < 256; ++k) {
            float w = Wa0[k * 256 + h];
            c0 += yl[0][k] * w; c1 += yl[1][k] * w;
        }
        rWa[r0 * 256 + h] = c0; rWa[(r0 + 1) * 256 + h] = c1;
    }
}

// ---- 3. update via MFMA split-bf16, 1024 threads / 16 waves (16 cols each) ----
// Both GEMMs 2-term. Optional fused scores phase (last robot update).
__global__ __launch_bounds__(1024) void k_update_mfma(
        float* __restrict__ state, const float* __restrict__ agg,
        const unsigned short* __restrict__ WTm,   // [hi 256x512]
        const float* __restrict__ bvec, const float* __restrict__ g, const float* __restrict__ be,
        const unsigned short* __restrict__ WT2a,  // [hi 256x256]
        float* __restrict__ out2a,
        const unsigned short* __restrict__ WT2b, const float* __restrict__ b2b,
        float* __restrict__ out2b,
        const float* __restrict__ tSTg, const float* __restrict__ Ws2v,
        const float* __restrict__ bs2v, float* __restrict__ scoresOut) {
    int r0 = blockIdx.x * 16;
    int t = threadIdx.x;
    int w = t >> 6, lane = t & 63;
    int c16 = lane & 15, kg = lane >> 4;
    int col = (w << 4) | c16;

    __shared__ unsigned short Ahi[16 * 512];
    __shared__ unsigned short Alo[16 * 512];
    __shared__ unsigned short Yhi[16 * 256];
    __shared__ unsigned short Ylo[16 * 256];
    __shared__ float red[16][16][2];

    // preload first 4 main-GEMM B fragments (in flight across the staging phase)
    const unsigned short* Bh0 = WTm + col * 512 + kg * 8;
    bf16x8 bp0 = *(const bf16x8*)(Bh0);
    bf16x8 bp1 = *(const bf16x8*)(Bh0 + 32);
    bf16x8 bp2 = *(const bf16x8*)(Bh0 + 64);
    bf16x8 bp3 = *(const bf16x8*)(Bh0 + 96);

    // stage A = [state | agg] rows r0..r0+15 as swizzled hi/lo bf16 (8 elems/thread)
    {
        int row = t & 15, kq = t >> 4;   // kq 0..63 -> 8 K-elems each
        const float* src = (kq < 32) ? (state + (r0 + row) * 256 + kq * 8)
                                     : (agg + (r0 + row) * 256 + (kq - 32) * 8);
        float4 a = *(const float4*)(src);
        float4 b2 = *(const float4*)(src + 4);
        unsigned short h[8], lo[8];
        split2(a.x, h[0], lo[0]); split2(a.y, h[1], lo[1]);
        split2(a.z, h[2], lo[2]); split2(a.w, h[3], lo[3]);
        split2(b2.x, h[4], lo[4]); split2(b2.y, h[5], lo[5]);
        split2(b2.z, h[6], lo[6]); split2(b2.w, h[7], lo[7]);
        int byte = row * 1024 + kq * 16;
        byte ^= (row & 7) << 4;
        ushort4* ph = (ushort4*)((char*)Ahi + byte);
        ph[0] = make_ushort4(h[0], h[1], h[2], h[3]);
        ph[1] = make_ushort4(h[4], h[5], h[6], h[7]);
        ushort4* pl = (ushort4*)((char*)Alo + byte);
        pl[0] = make_ushort4(lo[0], lo[1], lo[2], lo[3]);
        pl[1] = make_ushort4(lo[4], lo[5], lo[6], lo[7]);
    }
    __syncthreads();

    // main GEMM: K=512, 2-term split, 1 col-tile per wave
    f32x4 acc = f32x4{0.f, 0.f, 0.f, 0.f};
#pragma unroll
    for (int ks = 0; ks < 16; ++ks) {
        int ab = c16 * 1024 + ks * 64 + kg * 16;
        ab ^= (c16 & 7) << 4;
        bf16x8 ah = *(const bf16x8*)((const char*)Ahi + ab);
        bf16x8 al = *(const bf16x8*)((const char*)Alo + ab);
        bf16x8 bh = (ks == 0) ? bp0 : (ks == 1) ? bp1 : (ks == 2) ? bp2 : (ks == 3) ? bp3
                                  : *(const bf16x8*)(Bh0 + ks * 32);
        acc = __builtin_amdgcn_mfma_f32_16x16x32_bf16(ah, bh, acc, 0, 0, 0);
        acc = __builtin_amdgcn_mfma_f32_16x16x32_bf16(al, bh, acc, 0, 0, 0);
    }

    // residual + bias
    float x[4];
    {
        float bv = bvec[col];
#pragma unroll
        for (int r = 0; r < 4; ++r) {
            int row = kg * 4 + r;
            x[r] = acc[r] + state[(r0 + row) * 256 + col] + bv;
        }
    }

    // LN stats: reduce over 16 cols in-wave, then 16 waves via LDS
    float s[4], q[4];
#pragma unroll
    for (int r = 0; r < 4; ++r) {
        s[r] = x[r];
        q[r] = x[r] * x[r];
#pragma unroll
        for (int m = 1; m < 16; m <<= 1) {
            s[r] += __shfl_xor(s[r], m);
            q[r] += __shfl_xor(q[r], m);
        }
    }
    if (c16 == 0) {
#pragma unroll
        for (int r = 0; r < 4; ++r) {
            red[w][kg * 4 + r][0] = s[r];
            red[w][kg * 4 + r][1] = q[r];
        }
    }
    __syncthreads();
    float mr[4], rsr[4];
#pragma unroll
    for (int r = 0; r < 4; ++r) {
        int row = kg * 4 + r;
        float S = 0.f, Q = 0.f;
#pragma unroll
        for (int w2 = 0; w2 < 16; ++w2) { S += red[w2][row][0]; Q += red[w2][row][1]; }
        float m = S * (1.f / 256.f);
        float v = Q * (1.f / 256.f) - m * m;
        mr[r] = m;
        rsr[r] = rsqrtf(v + 1e-5f);
    }

    // y = LN(x): store to state + stage bf16 hi/lo into LDS (swizzled)
    {
        float gg = g[col], bb = be[col];
#pragma unroll
        for (int r = 0; r < 4; ++r) {
            int row = kg * 4 + r;
            float y = (x[r] - mr[r]) * rsr[r] * gg + bb;
            state[(r0 + row) * 256 + col] = y;
            unsigned short yh, yl2;
            split2(y, yh, yl2);
            int byte = (row * 512 + col * 2) ^ ((row & 7) << 4);
            *(unsigned short*)((char*)Yhi + byte) = yh;
            *(unsigned short*)((char*)Ylo + byte) = yl2;
        }
    }
    __syncthreads();

    // fused GEMM(s), 2-term: y @ W2a, optional y @ W2b + b2b (-> out2b T)
    f32x4 acc2 = f32x4{0.f, 0.f, 0.f, 0.f};
    f32x4 acc3 = f32x4{0.f, 0.f, 0.f, 0.f};
    const unsigned short* B2h0 = WT2a + col * 256 + kg * 8;
    const unsigned short* B3h0 = WT2b ? (WT2b + col * 256 + kg * 8) : B2h0;
    int haveB = (WT2b != nullptr);
#pragma unroll 4
    for (int ks = 0; ks < 8; ++ks) {
        int ab = c16 * 512 + ks * 64 + kg * 16;
        ab ^= (c16 & 7) << 4;
        bf16x8 ah = *(const bf16x8*)((const char*)Yhi + ab);
        bf16x8 al = *(const bf16x8*)((const char*)Ylo + ab);
        bf16x8 bh = *(const bf16x8*)(B2h0 + ks * 32);
        acc2 = __builtin_amdgcn_mfma_f32_16x16x32_bf16(ah, bh, acc2, 0, 0, 0);
        acc2 = __builtin_amdgcn_mfma_f32_16x16x32_bf16(al, bh, acc2, 0, 0, 0);
        if (haveB) {
            bf16x8 bh3 = *(const bf16x8*)(B3h0 + ks * 32);
            acc3 = __builtin_amdgcn_mfma_f32_16x16x32_bf16(ah, bh3, acc3, 0, 0, 0);
            acc3 = __builtin_amdgcn_mfma_f32_16x16x32_bf16(al, bh3, acc3, 0, 0, 0);
        }
    }
    if (!scoresOut) {
#pragma unroll
        for (int r = 0; r < 4; ++r) {
            int row = kg * 4 + r;
            out2a[(r0 + row) * 256 + col] = acc2[r];
        }
    }
    if (haveB) {
        float bb2 = b2b[col];
#pragma unroll
        for (int r = 0; r < 4; ++r) {
            int grow = r0 + kg * 4 + r;
            int b0 = grow >> 6, j = grow & 63;
            out2b[(b0 * 256 + col) * 64 + j] = acc3[r] + bb2;
        }
    }

    // fused scores phase (last robot update): rS rows live in LDS (alias Ahi)
    if (scoresOut) {
        float* rSl = (float*)Ahi;        // 16x256 f32 = 16KB, Ahi is dead
#pragma unroll
        for (int r = 0; r < 4; ++r)
            rSl[(kg * 4 + r) * 256 + col] = acc2[r];
        __syncthreads();
        int il = t >> 6, j = t & 63;     // 16 rows x 64 cols = 1024 threads
        int grow = r0 + il, b0 = grow >> 6;
        const float* ts = tSTg + b0 * 16384 + j;
        const float* rsrow = rSl + il * 256;
        float accs = bs2v[0];
        for (int h = 0; h < 256; ++h)
            accs += fmaxf(rsrow[h] + ts[h * 64], 0.f) * Ws2v[h];
        scoresOut[grow * 64 + j] = accs;
    }
}

// ---- 4. bigpass: hoisted loads; prefetch issued mid-kernel, consumed at end ----
__global__ __launch_bounds__(256) void k_bigpass(const unsigned short* __restrict__ edge_bf,
                                                 const unsigned short* __restrict__ WcT,
                                                 const float* __restrict__ bc,
                                                 const float* __restrict__ rowbias,
                                                 float* __restrict__ agg,
                                                 int mode,
                                                 const unsigned short* __restrict__ prefA,
                                                 const unsigned short* __restrict__ prefB,
                                                 int nb) {            // nb = uint4 count of B slice
    int wg = blockIdx.x;                 // 512 = b*64 + jj
    int b = wg >> 6, jj = wg & 63;
    int w = threadIdx.x >> 6, lane = threadIdx.x & 63;
    int row16 = lane & 15, kgrp = lane >> 4;

    int rstride = (mode == 0) ? 8192 : 128;
    const unsigned short* Ap = edge_bf + b * 524288 + ((mode == 0) ? jj * 128 : jj * 8192)
                             + row16 * rstride + 8 * kgrp;
    const unsigned short* Bp = WcT + (64 * w + row16) * 128 + 8 * kgrp;

    // hoist ALL fragment loads: one latency window
    bf16x8 av[4][4], bv[4][4];
#pragma unroll
    for (int kk = 0; kk < 4; ++kk) {
#pragma unroll
        for (int mi = 0; mi < 4; ++mi)
            av[mi][kk] = *(const bf16x8*)(Ap + mi * 16 * rstride + kk * 32);
#pragma unroll
        for (int ni = 0; ni < 4; ++ni)
            bv[ni][kk] = *(const bf16x8*)(Bp + ni * 2048 + kk * 32);
    }
    __builtin_amdgcn_sched_barrier(0);

    f32x4 acc[4][4];
#pragma unroll
    for (int mi = 0; mi < 4; ++mi)
#pragma unroll
        for (int ni = 0; ni < 4; ++ni) acc[mi][ni] = f32x4{0.f, 0.f, 0.f, 0.f};
#pragma unroll
    for (int kk = 0; kk < 4; ++kk)
#pragma unroll
        for (int mi = 0; mi < 4; ++mi)
#pragma unroll
            for (int ni = 0; ni < 4; ++ni)
                acc[mi][ni] = __builtin_amdgcn_mfma_f32_16x16x32_bf16(av[mi][kk], bv[ni][kk], acc[mi][ni], 0, 0, 0);

    // issue prefetch loads now (next update's weight panels, 1/64 slice)
    int s = (blockIdx.x >> 3) & 63;
    const uint4* pa = (const uint4*)prefA + (long)s * 256;
    const uint4* pb = (const uint4*)prefB + (long)s * nb;
    uint4 pf0 = pa[threadIdx.x];
    uint4 pf2;
    int i0 = threadIdx.x & (nb - 1);
    pf2 = pb[i0];
    uint4 pf3;
    int big = (nb > 128);
    if (big) pf3 = pb[128 + (threadIdx.x & 255)];
    __builtin_amdgcn_sched_barrier(0);

    const float* rb = rowbias + (b * 64) * 256;
    float colsum[4] = {0.f, 0.f, 0.f, 0.f};
#pragma unroll
    for (int ni = 0; ni < 4; ++ni) {
        int col = 64 * w + 16 * ni + row16;
        float bch = bc[col];
#pragma unroll
        for (int mi = 0; mi < 4; ++mi) {
            int rbase = 16 * mi + 4 * kgrp;
#pragma unroll
            for (int r = 0; r < 4; ++r) {
                float v = acc[mi][ni][r] + rb[(rbase + r) * 256 + col] + bch;
                colsum[ni] += fmaxf(v, 0.f);
            }
        }
    }
#pragma unroll
    for (int ni = 0; ni < 4; ++ni) {
        colsum[ni] += __shfl_xor(colsum[ni], 16);
        colsum[ni] += __shfl_xor(colsum[ni], 32);
    }
    if (kgrp == 0) {
        float* o = agg + (b * 64 + jj) * 256 + 64 * w + row16;
#pragma unroll
        for (int ni = 0; ni < 4; ++ni) o[16 * ni] = colsum[ni] * (1.f / 64.f);
    }

    unsigned accp = pf0.x ^ pf0.w ^ pf2.z;
    if (big) accp ^= pf3.x;
    asm volatile("" :: "v"(accp));
}

// ---- 5. sinkhorn: 8 WGs x 1024, v[4]/thread ----
__global__ __launch_bounds__(1024) void k_sinkhorn(const float* __restrict__ scores,
                                                   float* __restrict__ probs) {
    int b = blockIdx.x;
    int t = threadIdx.x;
    int j = t & 63, rg = t >> 6;         // 16 row-groups x 4 rows
    float v[4];
    const float* src = scores + b * 4096 + rg * 256 + j;
#pragma unroll
    for (int k = 0; k < 4; ++k) v[k] = src[k * 64];

    __shared__ float lm_s[2][16][64];
    __shared__ float ps_s[2][16][64];

    for (int it = 0; it < 10; ++it) {
#pragma unroll
        for (int k = 0; k < 4; ++k) {
            float m = v[k];
#pragma unroll
            for (int s = 1; s < 64; s <<= 1) m = fmaxf(m, __shfl_xor(m, s));
            float e = __expf(v[k] - m), ss = e;
#pragma unroll
            for (int s = 1; s < 64; s <<= 1) ss += __shfl_xor(ss, s);
            v[k] -= m + __logf(ss);
        }
        int p = it & 1;
        float lm = fmaxf(fmaxf(v[0], v[1]), fmaxf(v[2], v[3]));
        float ps = __expf(v[0] - lm) + __expf(v[1] - lm) + __expf(v[2] - lm) + __expf(v[3] - lm);
        lm_s[p][rg][j] = lm; ps_s[p][rg][j] = ps;
        __syncthreads();
        float M = lm_s[p][0][j];
#pragma unroll
        for (int g2 = 1; g2 < 16; ++g2) M = fmaxf(M, lm_s[p][g2][j]);
        float S = 0.f;
#pragma unroll
        for (int g2 = 0; g2 < 16; ++g2) S += ps_s[p][g2][j] * __expf(lm_s[p][g2][j] - M);
        float lse = M + __logf(S);
#pragma unroll
        for (int k = 0; k < 4; ++k) v[k] -= lse;
    }
    float* dst = probs + b * 4096 + rg * 256 + j;
#pragma unroll
    for (int k = 0; k < 4; ++k) dst[k * 64] = __expf(v[k]);
}

extern "C" void kernel_launch(void* const* d_in, const int* in_sizes, int n_in,
                              void* d_out, int out_size, void* d_ws, size_t ws_size,
                              hipStream_t stream) {
    const float* robot_raw = (const float*)d_in[0];
    const float* edge_raw  = (const float*)d_in[1];
    const float* Wp    = (const float*)d_in[2];
    const float* bp    = (const float*)d_in[3];
    const float* W_r2t = (const float*)d_in[4];
    const float* b_r2t = (const float*)d_in[5];
    const float* W_pt  = (const float*)d_in[6];
    const float* b_pt  = (const float*)d_in[7];
    const float* g_t   = (const float*)d_in[8];
    const float* be_t  = (const float*)d_in[9];
    const float* W_t2r = (const float*)d_in[10];
    const float* b_t2r = (const float*)d_in[11];
    const float* W_pr  = (const float*)d_in[12];
    const float* b_pr  = (const float*)d_in[13];
    const float* g_r   = (const float*)d_in[14];
    const float* be_r  = (const float*)d_in[15];
    const float* Ws1   = (const float*)d_in[16];
    const float* bs1   = (const float*)d_in[17];
    const float* Ws2   = (const float*)d_in[18];
    const float* bs2   = (const float*)d_in[19];

    char* ws = (char*)d_ws;
    unsigned short* edge_bf = (unsigned short*)(ws);            // 8,388,608
    float* traw     = (float*)(ws + 8388608);                   //   262,144
    float* robot_h  = (float*)(ws + 8650752);                   //   524,288
    float* target_h = (float*)(ws + 9175040);                   //   524,288
    unsigned short* WcT = (unsigned short*)(ws + 9699328);      //   393,216
    float* bc       = (float*)(ws + 10092544);                  //     6,144
    float* rWa      = (float*)(ws + 10098688);                  //   524,288
    float* tWa      = (float*)(ws + 10622976);                  //   524,288
    float* agg      = (float*)(ws + 11147264);                  //   524,288
    float* rS       = (float*)(ws + 11671552);                  //   524,288 (dead store target)
    float* tST      = (float*)(ws + 12195840);                  //   524,288
    unsigned short* WTbig = (unsigned short*)(ws + 12720128);   // hi planes (mat stride 262144 elems)
    unsigned short* WT2   = (unsigned short*)(ws + 15865856);   // hi planes (mat stride 65536 elems)

    float* out    = (float*)d_out;
    float* probs  = out;            // output 0
    float* scores = out + 32768;    // output 1

    hipLaunchKernelGGL(k_prep_w, dim3(4614), dim3(256), 0, stream,
                       edge_raw, edge_bf, traw,
                       Wp, bp, W_r2t, b_r2t, W_t2r, b_t2r, W_pt, W_pr, Ws1, WcT, bc, WTbig, WT2);
    hipLaunchKernelGGL(k_proj, dim3(512), dim3(256), 0, stream,
                       robot_raw, traw, Wp, bp, W_r2t, robot_h, target_h, rWa);

    for (int l = 0; l < 3; ++l) {
        // r2t bigpass + prefetch of the target-update weights (hi planes)
        {
            const unsigned short* pA = WTbig + (2 * l) * 262144;
            const unsigned short* pB = WT2 + (2 * l) * 65536;
            int nb = (l == 2) ? 384 : 128;                     // l==2 covers mats 4..6
            hipLaunchKernelGGL(k_bigpass, dim3(512), dim3(256), 0, stream,
                               edge_bf, WcT + (2 * l) * 32768, bc + (2 * l) * 256, rWa, agg, 0,
                               pA, pB, nb);
        }
        const unsigned short* W2b = (l == 2) ? (WT2 + 6 * 65536) : nullptr;
        const float* b2b = (l == 2) ? bs1 : nullptr;
        float* o2b = (l == 2) ? tST : nullptr;
        hipLaunchKernelGGL(k_update_mfma, dim3(32), dim3(1024), 0, stream,
                           target_h, agg, WTbig + (2 * l) * 262144,
                           b_pt + l * 256, g_t + l * 256, be_t + l * 256,
                           WT2 + (2 * l) * 65536, tWa, W2b, b2b, o2b,
                           (const float*)nullptr, (const float*)nullptr,
                           (const float*)nullptr, (float*)nullptr);
        // t2r bigpass + prefetch of the robot-update weights
        {
            const unsigned short* pA = WTbig + (2 * l + 1) * 262144;
            int m2 = (l < 2) ? (2 * l + 1) : 5;
            const unsigned short* pB = WT2 + m2 * 65536;
            hipLaunchKernelGGL(k_bigpass, dim3(512), dim3(256), 0, stream,
                               edge_bf, WcT + (2 * l + 1) * 32768, bc + (2 * l + 1) * 256, tWa, agg, 1,
                               pA, pB, 128);
        }
        const unsigned short* W2a = (l < 2) ? (WT2 + (2 * l + 1) * 65536) : (WT2 + 5 * 65536);
        float* o2a = (l < 2) ? rWa : rS;
        const float* fTST = (l == 2) ? tST : nullptr;
        const float* fWs2 = (l == 2) ? Ws2 : nullptr;
        const float* fbs2 = (l == 2) ? bs2 : nullptr;
        float* fScores    = (l == 2) ? scores : nullptr;
        hipLaunchKernelGGL(k_update_mfma, dim3(32), dim3(1024), 0, stream,
                           robot_h, agg, WTbig + (2 * l + 1) * 262144,
                           b_pr + l * 256, g_r + l * 256, be_r + l * 256,
                           W2a, o2a, (const unsigned short*)nullptr, (const float*)nullptr, (float*)nullptr,
                           fTST, fWs2, fbs2, fScores);
    }

    hipLaunchKernelGGL(k_sinkhorn, dim3(8), dim3(1024), 0, stream, scores, probs);
}